// Round 3
// baseline (515.941 us; speedup 1.0000x reference)
//
#include <hip/hip_runtime.h>
#include <math.h>

#define B_ 128
#define NTOK 577
#define P_ 576
#define D_ 768
#define G_ 17
#define KOCC 10
#define INV_TEMP 10.0f

// ws layout (floats):
//   wt     : [17][768] transposed group_weights  @ 0
//   sim    : [B_][P_]                            @ WT_SZ
//   mask   : [B_][P_]                            @ WT_SZ +   B_*P_
//   clsinv : [B_]                                @ WT_SZ + 2*B_*P_
#define WT_SZ (G_ * D_)

// K0: blocks 0..127: feats[b][0]=cls, zero feats[b][1..17], clsinv.
//     blocks 128..144: transpose gw (D,G) -> wt (G,D).
__global__ __launch_bounds__(256) void k0_cls(const float* __restrict__ x,
                                              const float* __restrict__ gw,
                                              float* __restrict__ feats,
                                              float* __restrict__ clsinv,
                                              float* __restrict__ wt) {
    if (blockIdx.x >= B_) {
        int g = blockIdx.x - B_;
        for (int d = threadIdx.x; d < D_; d += 256)
            wt[g * D_ + d] = gw[d * G_ + g];
        return;
    }
    int b = blockIdx.x;
    const float* cls = x + (size_t)b * NTOK * D_;
    float* fb = feats + (size_t)b * 18 * D_;
    float ss = 0.f;
    for (int i = threadIdx.x; i < D_ / 4; i += 256) {
        float4 v = ((const float4*)cls)[i];
        ((float4*)fb)[i] = v;
        ss = fmaf(v.x, v.x, fmaf(v.y, v.y, fmaf(v.z, v.z, fmaf(v.w, v.w, ss))));
    }
    float4 z = {0.f, 0.f, 0.f, 0.f};
    for (int i = threadIdx.x; i < G_ * D_ / 4; i += 256)
        ((float4*)(fb + D_))[i] = z;
    #pragma unroll
    for (int off = 32; off; off >>= 1) ss += __shfl_xor(ss, off, 64);
    __shared__ float red[4];
    int wave = threadIdx.x >> 6, lane = threadIdx.x & 63;
    if (lane == 0) red[wave] = ss;
    __syncthreads();
    if (threadIdx.x == 0) {
        float t = red[0] + red[1] + red[2] + red[3];
        clsinv[b] = 1.0f / fmaxf(sqrtf(t), 1e-12f);
    }
}

// K1: register-tiled scores + sim. grid (9, B_), block 256 (4 waves).
// Block = 64 patches. Lane owns 4 patches (m), 16-lane k-slice (lr).
// Per 64-dim chunk: stage 18 rows (17 wt + cls) in LDS (double-buffered),
// 1 ds_read_b128 per row feeds 16 FMAs. Raw scores -> LDS tile; writeout
// phase does the softmax column-wise and streams attn out coalesced.
__global__ __launch_bounds__(256) void k1_score(const float* __restrict__ x,
                                                const float* __restrict__ wt,
                                                const float* __restrict__ clsinv,
                                                float* __restrict__ sim,
                                                float* __restrict__ attn) {
    __shared__ __align__(16) float buf[2][18 * 64];
    __shared__ __align__(16) float atile[19 * 68];   // rows 0..16 scores, 17 clsdot, 18 sumsq
    int tid = threadIdx.x;
    int b = blockIdx.y, chunk = blockIdx.x;
    const float* clsrow = x + (size_t)b * NTOK * D_;

    // stage chunk 0
    for (int i = tid; i < 288; i += 256) {
        int r = i >> 4, c = i & 15;
        const float* src = (r < 17) ? (wt + r * D_ + c * 4) : (clsrow + c * 4);
        *(float4*)&buf[0][r * 64 + c * 4] = *(const float4*)src;
    }
    int lane = tid & 63, wave = tid >> 6;
    int lr = lane & 15, row4 = lane >> 4;
    int pbase = wave * 16 + row4 * 4;               // 0..60 within block tile
    const float* xp0 = x + ((size_t)(b * NTOK + 1 + chunk * 64 + pbase)) * D_ + lr * 4;

    float4 xv[4], xn[4];
    #pragma unroll
    for (int m = 0; m < 4; ++m) xv[m] = *(const float4*)(xp0 + (size_t)m * D_);

    float s[19][4];
    #pragma unroll
    for (int i = 0; i < 19; ++i)
        #pragma unroll
        for (int m = 0; m < 4; ++m) s[i][m] = 0.f;
    __syncthreads();

    for (int kc = 0; kc < 12; ++kc) {
        int cb = kc & 1, nb = cb ^ 1;
        if (kc < 11) {
            #pragma unroll
            for (int m = 0; m < 4; ++m)
                xn[m] = *(const float4*)(xp0 + (kc + 1) * 64 + (size_t)m * D_);
            for (int i = tid; i < 288; i += 256) {
                int r = i >> 4, c = i & 15;
                const float* src = (r < 17) ? (wt + r * D_ + (kc + 1) * 64 + c * 4)
                                            : (clsrow + (kc + 1) * 64 + c * 4);
                *(float4*)&buf[nb][r * 64 + c * 4] = *(const float4*)src;
            }
        }
        #pragma unroll
        for (int g = 0; g < 18; ++g) {
            float4 w4 = *(const float4*)&buf[cb][g * 64 + lr * 4];
            #pragma unroll
            for (int m = 0; m < 4; ++m)
                s[g][m] = fmaf(xv[m].x, w4.x, fmaf(xv[m].y, w4.y,
                          fmaf(xv[m].z, w4.z, fmaf(xv[m].w, w4.w, s[g][m]))));
        }
        #pragma unroll
        for (int m = 0; m < 4; ++m)
            s[18][m] = fmaf(xv[m].x, xv[m].x, fmaf(xv[m].y, xv[m].y,
                       fmaf(xv[m].z, xv[m].z, fmaf(xv[m].w, xv[m].w, s[18][m]))));
        #pragma unroll
        for (int m = 0; m < 4; ++m) xv[m] = xn[m];
        __syncthreads();
    }

    // reduce over the 16-lane k-slice
    #pragma unroll
    for (int off = 8; off >= 1; off >>= 1)
        #pragma unroll
        for (int i = 0; i < 19; ++i)
            #pragma unroll
            for (int m = 0; m < 4; ++m)
                s[i][m] += __shfl_xor(s[i][m], off, 16);

    // lane lr deposits row lr (lane 15 also rows 16..18) as float4 over m
    #pragma unroll
    for (int g = 0; g < 19; ++g) {
        if (lr == ((g < 16) ? g : 15)) {
            float4 v = {s[g][0], s[g][1], s[g][2], s[g][3]};
            *(float4*)&atile[g * 68 + pbase] = v;
        }
    }
    __syncthreads();

    // writeout: thread pp<64 does softmax for its patch column + sim
    if (tid < 64) {
        int p = chunk * 64 + tid;
        float v[17];
        float mx = -3.0e38f;
        #pragma unroll
        for (int g = 0; g < 17; ++g) {
            v[g] = atile[g * 68 + tid];
            mx = fmaxf(mx, v[g]);
        }
        float tot = 0.f;
        #pragma unroll
        for (int g = 0; g < 17; ++g) {
            v[g] = __expf((v[g] - mx) * INV_TEMP);
            tot += v[g];
        }
        float inv = 1.0f / tot;
        float* ap = attn + ((size_t)b * G_) * P_ + p;
        #pragma unroll
        for (int g = 0; g < 17; ++g) ap[(size_t)g * P_] = v[g] * inv;
        float cd = atile[17 * 68 + tid];
        float sq = atile[18 * 68 + tid];
        sim[(size_t)b * P_ + p] = cd * clsinv[b] / fmaxf(sqrtf(sq), 1e-12f);
    }
}

// K2: per batch (1 wave): select 10 smallest sims (ties -> lower index),
// write mask, overwrite occluded attn columns with 1/17.
__global__ __launch_bounds__(64) void k2_occl(const float* __restrict__ sim,
                                              float* __restrict__ mask,
                                              float* __restrict__ attn) {
    int b = blockIdx.x, lane = threadIdx.x;
    int base = lane * 9;                      // 64*9 == 576
    float v[9];
    bool occ[9];
    #pragma unroll
    for (int j = 0; j < 9; ++j) {
        v[j] = sim[(size_t)b * P_ + base + j];
        occ[j] = false;
    }
    int wins[KOCC];
    for (int t = 0; t < KOCC; ++t) {
        float mv = 3.0e38f;
        int mi = 1 << 30;
        #pragma unroll
        for (int j = 0; j < 9; ++j) {
            if (v[j] < mv) { mv = v[j]; mi = base + j; }
        }
        #pragma unroll
        for (int off = 1; off < 64; off <<= 1) {
            float ov = __shfl_xor(mv, off, 64);
            int oi = __shfl_xor(mi, off, 64);
            if (ov < mv || (ov == mv && oi < mi)) { mv = ov; mi = oi; }
        }
        wins[t] = mi;
        int loc = mi - base;
        if (loc >= 0 && loc < 9) { v[loc] = 3.0e38f; occ[loc] = true; }
    }
    #pragma unroll
    for (int j = 0; j < 9; ++j)
        mask[(size_t)b * P_ + base + j] = occ[j] ? 0.0f : 1.0f;
    const float u = 1.0f / 17.0f;
    for (int t = 0; t < KOCC; ++t) {
        if (lane < G_) attn[((size_t)b * G_ + lane) * P_ + wins[t]] = u;
    }
}

// K3: group features. grid (6, B_), block 192 (3 waves). Thread owns d float4
// (192*4 == 768). attn*mask staged in LDS; broadcast b128 reads; 4 x-float4
// loads in flight; 17 float4 register accumulators; atomicAdd at the end.
#define PC_ 96
__global__ __launch_bounds__(192) void k3_gf(const float* __restrict__ x,
                                             const float* __restrict__ attn,
                                             const float* __restrict__ mask,
                                             float* __restrict__ feats) {
    __shared__ __align__(16) float am[G_ * PC_];
    int tid = threadIdx.x;
    int pc = blockIdx.x, b = blockIdx.y;
    int p0 = pc * PC_;

    for (int i = tid; i < G_ * PC_; i += 192) {
        int g = i / PC_;
        int pp = i - g * PC_;
        am[i] = attn[((size_t)b * G_ + g) * P_ + p0 + pp] * mask[(size_t)b * P_ + p0 + pp];
    }
    __syncthreads();

    const float* xb = x + ((size_t)(b * NTOK) + 1 + p0) * D_ + tid * 4;
    float4 acc[G_];
    #pragma unroll
    for (int g = 0; g < G_; ++g) acc[g] = make_float4(0.f, 0.f, 0.f, 0.f);

    for (int pp = 0; pp < PC_; pp += 4) {
        float4 x0 = *(const float4*)(xb + (size_t)(pp + 0) * D_);
        float4 x1 = *(const float4*)(xb + (size_t)(pp + 1) * D_);
        float4 x2 = *(const float4*)(xb + (size_t)(pp + 2) * D_);
        float4 x3 = *(const float4*)(xb + (size_t)(pp + 3) * D_);
        #pragma unroll
        for (int g = 0; g < G_; ++g) {
            float4 a = *(const float4*)&am[g * PC_ + pp];    // wave-uniform broadcast
            acc[g].x = fmaf(a.x, x0.x, fmaf(a.y, x1.x, fmaf(a.z, x2.x, fmaf(a.w, x3.x, acc[g].x))));
            acc[g].y = fmaf(a.x, x0.y, fmaf(a.y, x1.y, fmaf(a.z, x2.y, fmaf(a.w, x3.y, acc[g].y))));
            acc[g].z = fmaf(a.x, x0.z, fmaf(a.y, x1.z, fmaf(a.z, x2.z, fmaf(a.w, x3.z, acc[g].z))));
            acc[g].w = fmaf(a.x, x0.w, fmaf(a.y, x1.w, fmaf(a.z, x2.w, fmaf(a.w, x3.w, acc[g].w))));
        }
    }
    float* fb = feats + ((size_t)(b * 18) + 1) * D_ + tid * 4;
    #pragma unroll
    for (int g = 0; g < G_; ++g) {
        atomicAdd(fb + (size_t)g * D_ + 0, acc[g].x);
        atomicAdd(fb + (size_t)g * D_ + 1, acc[g].y);
        atomicAdd(fb + (size_t)g * D_ + 2, acc[g].z);
        atomicAdd(fb + (size_t)g * D_ + 3, acc[g].w);
    }
}

extern "C" void kernel_launch(void* const* d_in, const int* in_sizes, int n_in,
                              void* d_out, int out_size, void* d_ws, size_t ws_size,
                              hipStream_t stream) {
    const float* x  = (const float*)d_in[0];
    const float* gw = (const float*)d_in[1];
    float* feats = (float*)d_out;                               // B*18*D
    float* attn  = (float*)d_out + (size_t)B_ * 18 * D_;        // B*17*P
    float* wt     = (float*)d_ws;
    float* sim    = (float*)d_ws + WT_SZ;
    float* mask   = (float*)d_ws + WT_SZ + (size_t)B_ * P_;
    float* clsinv = (float*)d_ws + WT_SZ + (size_t)2 * B_ * P_;

    k0_cls<<<B_ + G_, 256, 0, stream>>>(x, gw, feats, clsinv, wt);
    k1_score<<<dim3(9, B_), 256, 0, stream>>>(x, wt, clsinv, sim, attn);
    k2_occl<<<B_, 64, 0, stream>>>(sim, mask, attn);
    k3_gf<<<dim3(P_ / PC_, B_), 192, 0, stream>>>(x, attn, mask, feats);
}

// Round 4
// 413.246 us; speedup vs baseline: 1.2485x; 1.2485x over previous
//
#include <hip/hip_runtime.h>
#include <math.h>

#define B_ 128
#define NTOK 577
#define P_ 576
#define D_ 768
#define G_ 17
#define KOCC 10
#define INV_TEMP 10.0f
#define U17 (1.0f / 17.0f)

// ws layout (float offsets):
#define OFF_WT 0                                // [17][768] transposed weights
#define OFF_SIM (G_ * D_)                       // [B][576]
#define OFF_CLSINV (OFF_SIM + B_ * P_)          // [B]
#define OFF_OCC (OFF_CLSINV + B_)               // [B][10] (ints)
#define OFF_GFP (OFF_OCC + B_ * KOCC)           // [nparts][B][17][768]
#define GFP_PART ((size_t)B_ * G_ * D_)

// K0: blocks 0..127: feats[b][0]=cls, clsinv[b]; optional zero of group rows
//     (only needed for the atomic fallback path). blocks 128..144: gw -> wt.
__global__ __launch_bounds__(256) void k0_cls(const float* __restrict__ x,
                                              const float* __restrict__ gw,
                                              float* __restrict__ feats,
                                              float* __restrict__ clsinv,
                                              float* __restrict__ wt,
                                              int zero_groups) {
    if (blockIdx.x >= B_) {
        int g = blockIdx.x - B_;
        for (int d = threadIdx.x; d < D_; d += 256)
            wt[g * D_ + d] = gw[d * G_ + g];
        return;
    }
    int b = blockIdx.x;
    const float* cls = x + (size_t)b * NTOK * D_;
    float* fb = feats + (size_t)b * 18 * D_;
    float ss = 0.f;
    for (int i = threadIdx.x; i < D_ / 4; i += 256) {
        float4 v = ((const float4*)cls)[i];
        ((float4*)fb)[i] = v;
        ss = fmaf(v.x, v.x, fmaf(v.y, v.y, fmaf(v.z, v.z, fmaf(v.w, v.w, ss))));
    }
    if (zero_groups) {
        float4 z = {0.f, 0.f, 0.f, 0.f};
        for (int i = threadIdx.x; i < G_ * D_ / 4; i += 256)
            ((float4*)(fb + D_))[i] = z;
    }
    #pragma unroll
    for (int off = 32; off; off >>= 1) ss += __shfl_xor(ss, off, 64);
    __shared__ float red[4];
    int wave = threadIdx.x >> 6, lane = threadIdx.x & 63;
    if (lane == 0) red[wave] = ss;
    __syncthreads();
    if (threadIdx.x == 0) {
        float t = red[0] + red[1] + red[2] + red[3];
        clsinv[b] = 1.0f / fmaxf(sqrtf(t), 1e-12f);
    }
}

// K1: register-tiled scores + sim. grid (9, B_), block 256 (4 waves).
__global__ __launch_bounds__(256) void k1_score(const float* __restrict__ x,
                                                const float* __restrict__ wt,
                                                const float* __restrict__ clsinv,
                                                float* __restrict__ sim,
                                                float* __restrict__ attn) {
    __shared__ __align__(16) float buf[2][18 * 64];
    __shared__ __align__(16) float atile[19 * 68];
    int tid = threadIdx.x;
    int b = blockIdx.y, chunk = blockIdx.x;
    const float* clsrow = x + (size_t)b * NTOK * D_;

    for (int i = tid; i < 288; i += 256) {
        int r = i >> 4, c = i & 15;
        const float* src = (r < 17) ? (wt + r * D_ + c * 4) : (clsrow + c * 4);
        *(float4*)&buf[0][r * 64 + c * 4] = *(const float4*)src;
    }
    int lane = tid & 63, wave = tid >> 6;
    int lr = lane & 15, row4 = lane >> 4;
    int pbase = wave * 16 + row4 * 4;
    const float* xp0 = x + ((size_t)(b * NTOK + 1 + chunk * 64 + pbase)) * D_ + lr * 4;

    float4 xv[4], xn[4];
    #pragma unroll
    for (int m = 0; m < 4; ++m) xv[m] = *(const float4*)(xp0 + (size_t)m * D_);

    float s[19][4];
    #pragma unroll
    for (int i = 0; i < 19; ++i)
        #pragma unroll
        for (int m = 0; m < 4; ++m) s[i][m] = 0.f;
    __syncthreads();

    for (int kc = 0; kc < 12; ++kc) {
        int cb = kc & 1, nb = cb ^ 1;
        if (kc < 11) {
            #pragma unroll
            for (int m = 0; m < 4; ++m)
                xn[m] = *(const float4*)(xp0 + (kc + 1) * 64 + (size_t)m * D_);
            for (int i = tid; i < 288; i += 256) {
                int r = i >> 4, c = i & 15;
                const float* src = (r < 17) ? (wt + r * D_ + (kc + 1) * 64 + c * 4)
                                            : (clsrow + (kc + 1) * 64 + c * 4);
                *(float4*)&buf[nb][r * 64 + c * 4] = *(const float4*)src;
            }
        }
        #pragma unroll
        for (int g = 0; g < 18; ++g) {
            float4 w4 = *(const float4*)&buf[cb][g * 64 + lr * 4];
            #pragma unroll
            for (int m = 0; m < 4; ++m)
                s[g][m] = fmaf(xv[m].x, w4.x, fmaf(xv[m].y, w4.y,
                          fmaf(xv[m].z, w4.z, fmaf(xv[m].w, w4.w, s[g][m]))));
        }
        #pragma unroll
        for (int m = 0; m < 4; ++m)
            s[18][m] = fmaf(xv[m].x, xv[m].x, fmaf(xv[m].y, xv[m].y,
                       fmaf(xv[m].z, xv[m].z, fmaf(xv[m].w, xv[m].w, s[18][m]))));
        #pragma unroll
        for (int m = 0; m < 4; ++m) xv[m] = xn[m];
        __syncthreads();
    }

    #pragma unroll
    for (int off = 8; off >= 1; off >>= 1)
        #pragma unroll
        for (int i = 0; i < 19; ++i)
            #pragma unroll
            for (int m = 0; m < 4; ++m)
                s[i][m] += __shfl_xor(s[i][m], off, 16);

    #pragma unroll
    for (int g = 0; g < 19; ++g) {
        if (lr == ((g < 16) ? g : 15)) {
            float4 v = {s[g][0], s[g][1], s[g][2], s[g][3]};
            *(float4*)&atile[g * 68 + pbase] = v;
        }
    }
    __syncthreads();

    if (tid < 64) {
        int p = chunk * 64 + tid;
        float v[17];
        float mx = -3.0e38f;
        #pragma unroll
        for (int g = 0; g < 17; ++g) {
            v[g] = atile[g * 68 + tid];
            mx = fmaxf(mx, v[g]);
        }
        float tot = 0.f;
        #pragma unroll
        for (int g = 0; g < 17; ++g) {
            v[g] = __expf((v[g] - mx) * INV_TEMP);
            tot += v[g];
        }
        float inv = 1.0f / tot;
        float* ap = attn + ((size_t)b * G_) * P_ + p;
        #pragma unroll
        for (int g = 0; g < 17; ++g) ap[(size_t)g * P_] = v[g] * inv;
        float cd = atile[17 * 68 + tid];
        float sq = atile[18 * 68 + tid];
        sim[(size_t)b * P_ + p] = cd * clsinv[b] / fmaxf(sqrtf(sq), 1e-12f);
    }
}

// K2: per batch (1 wave): 10 smallest sims (ties -> lower index), store occ
// indices, overwrite occluded attn columns with 1/17.
__global__ __launch_bounds__(64) void k2_occl(const float* __restrict__ sim,
                                              float* __restrict__ attn,
                                              int* __restrict__ occ_idx) {
    int b = blockIdx.x, lane = threadIdx.x;
    int base = lane * 9;
    float v[9];
    #pragma unroll
    for (int j = 0; j < 9; ++j) v[j] = sim[(size_t)b * P_ + base + j];
    int wins[KOCC];
    for (int t = 0; t < KOCC; ++t) {
        float mv = 3.0e38f;
        int mi = 1 << 30;
        #pragma unroll
        for (int j = 0; j < 9; ++j) {
            if (v[j] < mv) { mv = v[j]; mi = base + j; }
        }
        #pragma unroll
        for (int off = 1; off < 64; off <<= 1) {
            float ov = __shfl_xor(mv, off, 64);
            int oi = __shfl_xor(mi, off, 64);
            if (ov < mv || (ov == mv && oi < mi)) { mv = ov; mi = oi; }
        }
        wins[t] = mi;
        int loc = mi - base;
        if (loc >= 0 && loc < 9) v[loc] = 3.0e38f;
    }
    if (lane == 0) {
        #pragma unroll
        for (int t = 0; t < KOCC; ++t) occ_idx[b * KOCC + t] = wins[t];
    }
    #pragma unroll
    for (int t = 0; t < KOCC; ++t) {
        if (lane < G_) attn[((size_t)b * G_ + lane) * P_ + wins[t]] = U17;
    }
}

// K3 (partials path): grid (nparts, B_), block 192. Thread owns a d-float4.
// attn tile (post-k2: occluded cols already 1/17) broadcast from LDS;
// x loads register-prefetched; NO atomics — each block owns its gfp slab.
__global__ __launch_bounds__(192) void k3_part(const float* __restrict__ x,
                                               const float* __restrict__ attn,
                                               float* __restrict__ gfp,
                                               int ppp) {
    extern __shared__ float am[];           // [17][ppp]
    int tid = threadIdx.x;
    int pc = blockIdx.x, b = blockIdx.y;
    int p0 = pc * ppp;

    for (int i = tid; i < G_ * ppp; i += 192) {
        int g = i / ppp;
        int pp = i - g * ppp;
        am[i] = attn[((size_t)b * G_ + g) * P_ + p0 + pp];
    }
    __syncthreads();

    const float* xb = x + ((size_t)(b * NTOK) + 1 + p0) * D_ + tid * 4;
    float4 acc[G_];
    #pragma unroll
    for (int g = 0; g < G_; ++g) acc[g] = make_float4(0.f, 0.f, 0.f, 0.f);

    float4 c0 = *(const float4*)(xb + (size_t)0 * D_);
    float4 c1 = *(const float4*)(xb + (size_t)1 * D_);
    float4 c2 = *(const float4*)(xb + (size_t)2 * D_);
    float4 c3 = *(const float4*)(xb + (size_t)3 * D_);

    for (int pp = 0; pp < ppp; pp += 4) {
        float4 n0, n1, n2, n3;
        if (pp + 4 < ppp) {
            n0 = *(const float4*)(xb + (size_t)(pp + 4) * D_);
            n1 = *(const float4*)(xb + (size_t)(pp + 5) * D_);
            n2 = *(const float4*)(xb + (size_t)(pp + 6) * D_);
            n3 = *(const float4*)(xb + (size_t)(pp + 7) * D_);
        }
        #pragma unroll
        for (int g = 0; g < G_; ++g) {
            float4 a = *(const float4*)&am[g * ppp + pp];   // wave-uniform broadcast
            acc[g].x = fmaf(a.x, c0.x, fmaf(a.y, c1.x, fmaf(a.z, c2.x, fmaf(a.w, c3.x, acc[g].x))));
            acc[g].y = fmaf(a.x, c0.y, fmaf(a.y, c1.y, fmaf(a.z, c2.y, fmaf(a.w, c3.y, acc[g].y))));
            acc[g].z = fmaf(a.x, c0.z, fmaf(a.y, c1.z, fmaf(a.z, c2.z, fmaf(a.w, c3.z, acc[g].z))));
            acc[g].w = fmaf(a.x, c0.w, fmaf(a.y, c1.w, fmaf(a.z, c2.w, fmaf(a.w, c3.w, acc[g].w))));
        }
        c0 = n0; c1 = n1; c2 = n2; c3 = n3;
    }

    float* gb = gfp + ((size_t)(pc * B_ + b) * G_) * D_ + tid * 4;
    #pragma unroll
    for (int g = 0; g < G_; ++g) *(float4*)(gb + (size_t)g * D_) = acc[g];
}

// K3 (atomic fallback, only if ws too small): accumulates directly into
// zero-initialized feats group rows.
#define PC_ 96
__global__ __launch_bounds__(192) void k3_atomic(const float* __restrict__ x,
                                                 const float* __restrict__ attn,
                                                 float* __restrict__ feats) {
    __shared__ __align__(16) float am[G_ * PC_];
    int tid = threadIdx.x;
    int pc = blockIdx.x, b = blockIdx.y;
    int p0 = pc * PC_;
    for (int i = tid; i < G_ * PC_; i += 192) {
        int g = i / PC_;
        int pp = i - g * PC_;
        am[i] = attn[((size_t)b * G_ + g) * P_ + p0 + pp];
    }
    __syncthreads();
    const float* xb = x + ((size_t)(b * NTOK) + 1 + p0) * D_ + tid * 4;
    float4 acc[G_];
    #pragma unroll
    for (int g = 0; g < G_; ++g) acc[g] = make_float4(0.f, 0.f, 0.f, 0.f);
    for (int pp = 0; pp < PC_; pp += 4) {
        float4 x0 = *(const float4*)(xb + (size_t)(pp + 0) * D_);
        float4 x1 = *(const float4*)(xb + (size_t)(pp + 1) * D_);
        float4 x2 = *(const float4*)(xb + (size_t)(pp + 2) * D_);
        float4 x3 = *(const float4*)(xb + (size_t)(pp + 3) * D_);
        #pragma unroll
        for (int g = 0; g < G_; ++g) {
            float4 a = *(const float4*)&am[g * PC_ + pp];
            acc[g].x = fmaf(a.x, x0.x, fmaf(a.y, x1.x, fmaf(a.z, x2.x, fmaf(a.w, x3.x, acc[g].x))));
            acc[g].y = fmaf(a.x, x0.y, fmaf(a.y, x1.y, fmaf(a.z, x2.y, fmaf(a.w, x3.y, acc[g].y))));
            acc[g].z = fmaf(a.x, x0.z, fmaf(a.y, x1.z, fmaf(a.z, x2.z, fmaf(a.w, x3.z, acc[g].z))));
            acc[g].w = fmaf(a.x, x0.w, fmaf(a.y, x1.w, fmaf(a.z, x2.w, fmaf(a.w, x3.w, acc[g].w))));
        }
    }
    float* fb = feats + ((size_t)(b * 18) + 1) * D_ + tid * 4;
    #pragma unroll
    for (int g = 0; g < G_; ++g) {
        atomicAdd(fb + (size_t)g * D_ + 0, acc[g].x);
        atomicAdd(fb + (size_t)g * D_ + 1, acc[g].y);
        atomicAdd(fb + (size_t)g * D_ + 2, acc[g].z);
        atomicAdd(fb + (size_t)g * D_ + 3, acc[g].w);
    }
}

// K4: grid (B_), block 192. Sum partials (or read atomically-built feats),
// subtract (1/17)*sum of occluded patch rows, write final group features.
__global__ __launch_bounds__(192) void k4_fin(const float* __restrict__ x,
                                              const int* __restrict__ occ_idx,
                                              const float* __restrict__ gfp,
                                              int nparts,
                                              float* __restrict__ feats) {
    int b = blockIdx.x, tid = threadIdx.x;
    float* fb = feats + ((size_t)(b * 18) + 1) * D_ + tid * 4;
    float4 acc[G_];
    if (nparts == 0) {
        #pragma unroll
        for (int g = 0; g < G_; ++g) acc[g] = *(const float4*)(fb + (size_t)g * D_);
    } else {
        #pragma unroll
        for (int g = 0; g < G_; ++g) acc[g] = make_float4(0.f, 0.f, 0.f, 0.f);
        for (int pc = 0; pc < nparts; ++pc) {
            const float* gb = gfp + ((size_t)(pc * B_ + b) * G_) * D_ + tid * 4;
            #pragma unroll
            for (int g = 0; g < G_; ++g) {
                float4 v = *(const float4*)(gb + (size_t)g * D_);
                acc[g].x += v.x; acc[g].y += v.y; acc[g].z += v.z; acc[g].w += v.w;
            }
        }
    }
    float4 corr = make_float4(0.f, 0.f, 0.f, 0.f);
    for (int t = 0; t < KOCC; ++t) {
        int p = occ_idx[b * KOCC + t];
        float4 xo = *(const float4*)(x + ((size_t)(b * NTOK) + 1 + p) * D_ + tid * 4);
        corr.x += xo.x; corr.y += xo.y; corr.z += xo.z; corr.w += xo.w;
    }
    corr.x *= U17; corr.y *= U17; corr.z *= U17; corr.w *= U17;
    #pragma unroll
    for (int g = 0; g < G_; ++g) {
        float4 v = acc[g];
        v.x -= corr.x; v.y -= corr.y; v.z -= corr.z; v.w -= corr.w;
        *(float4*)(fb + (size_t)g * D_) = v;
    }
}

extern "C" void kernel_launch(void* const* d_in, const int* in_sizes, int n_in,
                              void* d_out, int out_size, void* d_ws, size_t ws_size,
                              hipStream_t stream) {
    const float* x  = (const float*)d_in[0];
    const float* gw = (const float*)d_in[1];
    float* feats = (float*)d_out;                               // B*18*D
    float* attn  = (float*)d_out + (size_t)B_ * 18 * D_;        // B*17*P
    float* wt      = (float*)d_ws + OFF_WT;
    float* sim     = (float*)d_ws + OFF_SIM;
    float* clsinv  = (float*)d_ws + OFF_CLSINV;
    int*   occ_idx = (int*)((float*)d_ws + OFF_OCC);
    float* gfp     = (float*)d_ws + OFF_GFP;

    int nparts = 0;
    for (int n = 4; n >= 1; n >>= 1) {
        if ((OFF_GFP + (size_t)n * GFP_PART) * 4 <= ws_size) { nparts = n; break; }
    }

    k0_cls<<<B_ + G_, 256, 0, stream>>>(x, gw, feats, clsinv, wt, nparts == 0);
    k1_score<<<dim3(9, B_), 256, 0, stream>>>(x, wt, clsinv, sim, attn);
    k2_occl<<<B_, 64, 0, stream>>>(sim, attn, occ_idx);
    if (nparts > 0) {
        int ppp = P_ / nparts;
        k3_part<<<dim3(nparts, B_), 192, G_ * ppp * 4, stream>>>(x, attn, gfp, ppp);
    } else {
        k3_atomic<<<dim3(P_ / PC_, B_), 192, 0, stream>>>(x, attn, feats);
    }
    k4_fin<<<B_, 192, 0, stream>>>(x, occ_idx, gfp, nparts, feats);
}